// Round 8
// baseline (226.492 us; speedup 1.0000x reference)
//
#include <hip/hip_runtime.h>
#include <hip/hip_bf16.h>

// FrequencyLayer: separable real DFT via bf16 MFMA.
// real[b,c,u,v] = sum_{i,j} x[i,j] cos(2pi(j*u+i*v)/N)
// imag[b,c,u,v] = -sum_{i,j} x[i,j] sin(2pi(j*u+i*v)/N), N=256, u,v in [0,128)
//
// v8: configuration flip. v7 was pinned at the 128-reg/wave cliff (64 VGPR +
// 64 AGPR) with 6 barriers/image herding 16 lockstep waves. Now:
//   - 1 block per image (grid 1024), 512 thr, 128KB dynamic LDS (full A1T/B1n)
//   - __launch_bounds__(512,2): 256 regs/wave budget, 8 waves/CU (occupancy
//     drop is deliberate - v2 proved TLP is not the constraint)
//   - stage 1: two u-half passes; tables read from L2 with 1-deep reg prefetch
//     (phase A staging deleted); X 2-deep prefetch, staggered (v7-proven)
//   - ONE barrier per image (was 6)
//   - stage 2: two 32x32 tile passes, tables 2-deep, nb = sb^0x8000 (v7-proven)
// All numerics identical to v7 (f2bf RNE, same swizzle, same MFMA groups).

typedef __attribute__((ext_vector_type(8))) short short8;   // 8 bf16 = 4 VGPR
typedef __attribute__((ext_vector_type(4))) short bf16x4;   // 4 bf16 = 8B
typedef __attribute__((ext_vector_type(4))) float f32x4;    // MFMA C/D frag

#define NN 256
#define KF 128
#define NIMG 1024

__device__ __align__(16) short g_Ct[KF * NN];   // cos(2pi*u*j/256)
__device__ __align__(16) short g_St[KF * NN];   // sin(2pi*u*j/256)
__device__ __align__(16) short g_Stn[KF * NN];  // -sin(2pi*u*j/256)

__device__ __forceinline__ short f2bf(float f) {
    union { float f; unsigned u; } v; v.f = f;
    unsigned r = v.u + 0x7FFFu + ((v.u >> 16) & 1u);  // RNE
    return (short)(r >> 16);
}

__global__ void gen_tables() {
    int tid = blockIdx.x * blockDim.x + threadIdx.x;
    if (tid >= KF * NN) return;
    int u = tid >> 8;
    int j = tid & 255;
    int phase = (u * j) & 255;                       // exploit periodicity, exact angle
    float ang = (float)phase * 0.02454369260617026f; // 2pi/256
    float s, c;
    sincosf(ang, &s, &c);
    g_Ct[tid]  = f2bf(c);
    g_St[tid]  = f2bf(s);
    g_Stn[tid] = f2bf(-s);
}

#define MFMA(a, b, c) __builtin_amdgcn_mfma_f32_16x16x32_bf16(a, b, c, 0, 0, 0)

__global__ __launch_bounds__(512, 2) void freq_dft(const float* __restrict__ x,
                                                   float* __restrict__ out) {
    // 128KB dynamic LDS: A1T [128u][256i] bf16 swizzled (64KB) | B1n (64KB)
    extern __shared__ __align__(16) char lds[];

    const int img = blockIdx.x;
    const float* __restrict__ X = x + (size_t)img * (NN * NN);
    float* __restrict__ outR = out + (size_t)img * (KF * KF);
    float* __restrict__ outI = outR + (size_t)NIMG * (KF * KF);

    const int lane = threadIdx.x & 63;
    const int wave = threadIdx.x >> 6;   // 0..7
    const int l15  = lane & 15;
    const int lk8  = (lane >> 4) << 3;   // A/B frag k-base (shorts/floats)
    const int lr4  = (lane >> 4) << 2;   // D frag row-base
    const int wst  = wave;               // stagger offset

    // ================= stage 1: X -> A1T/B1n, two u-half passes =================
    const int i0 = wave * 32;            // this wave's i-slice (32 rows)
    const float* __restrict__ xp0 = X + (i0 + l15) * NN + lk8;
    const float* __restrict__ xp1 = X + (i0 + 16 + l15) * NN + lk8;

    #pragma unroll 1
    for (int uh = 0; uh < 2; ++uh) {
        // table fragment base pointers for u-rows uh*64 + fu*16 + l15
        const short* __restrict__ tc0 = g_Ct  + (uh * 64 +  0 + l15) * NN + lk8;
        const short* __restrict__ tc1 = g_Ct  + (uh * 64 + 16 + l15) * NN + lk8;
        const short* __restrict__ tc2 = g_Ct  + (uh * 64 + 32 + l15) * NN + lk8;
        const short* __restrict__ tc3 = g_Ct  + (uh * 64 + 48 + l15) * NN + lk8;
        const short* __restrict__ ts0 = g_Stn + (uh * 64 +  0 + l15) * NN + lk8;
        const short* __restrict__ ts1 = g_Stn + (uh * 64 + 16 + l15) * NN + lk8;
        const short* __restrict__ ts2 = g_Stn + (uh * 64 + 32 + l15) * NN + lk8;
        const short* __restrict__ ts3 = g_Stn + (uh * 64 + 48 + l15) * NN + lk8;

        f32x4 accA[2][4], accB[2][4];    // [fi][fu] : D[i][u] fragments
        #pragma unroll
        for (int fi = 0; fi < 2; ++fi)
            #pragma unroll
            for (int fu = 0; fu < 4; ++fu) {
                accA[fi][fu] = (f32x4){0.f, 0.f, 0.f, 0.f};
                accB[fi][fu] = (f32x4){0.f, 0.f, 0.f, 0.f};
            }

        const int jA = (wst & 7) * 32;
        const int jB = ((wst + 1) & 7) * 32;
        // X 2-deep: a = tile t, b = tile t+1
        f32x4 a0 = *(const f32x4*)(xp0 + jA), a1 = *(const f32x4*)(xp0 + jA + 4);
        f32x4 a2 = *(const f32x4*)(xp1 + jA), a3 = *(const f32x4*)(xp1 + jA + 4);
        f32x4 b0 = *(const f32x4*)(xp0 + jB), b1 = *(const f32x4*)(xp0 + jB + 4);
        f32x4 b2 = *(const f32x4*)(xp1 + jB), b3 = *(const f32x4*)(xp1 + jB + 4);
        // tables 1-deep: cur = tile t
        short8 ca0 = *(const short8*)(tc0 + jA), ca1 = *(const short8*)(tc1 + jA);
        short8 ca2 = *(const short8*)(tc2 + jA), ca3 = *(const short8*)(tc3 + jA);
        short8 sa0 = *(const short8*)(ts0 + jA), sa1 = *(const short8*)(ts1 + jA);
        short8 sa2 = *(const short8*)(ts2 + jA), sa3 = *(const short8*)(ts3 + jA);

        #pragma unroll
        for (int t = 0; t < 8; ++t) {
            f32x4 c0 = a0, c1 = a1, c2 = a2, c3 = a3;
            a0 = b0; a1 = b1; a2 = b2; a3 = b3;
            if (t < 6) {   // issue X tile t+2
                const int jn = ((t + 2 + wst) & 7) * 32;
                b0 = *(const f32x4*)(xp0 + jn); b1 = *(const f32x4*)(xp0 + jn + 4);
                b2 = *(const f32x4*)(xp1 + jn); b3 = *(const f32x4*)(xp1 + jn + 4);
            }
            short8 nc0, nc1, nc2, nc3, ns0, ns1, ns2, ns3;
            if (t < 7) {   // issue table tile t+1
                const int j1 = ((t + 1 + wst) & 7) * 32;
                nc0 = *(const short8*)(tc0 + j1); nc1 = *(const short8*)(tc1 + j1);
                nc2 = *(const short8*)(tc2 + j1); nc3 = *(const short8*)(tc3 + j1);
                ns0 = *(const short8*)(ts0 + j1); ns1 = *(const short8*)(ts1 + j1);
                ns2 = *(const short8*)(ts2 + j1); ns3 = *(const short8*)(ts3 + j1);
            }
            short8 xb0, xb1;
            xb0[0] = f2bf(c0[0]); xb0[1] = f2bf(c0[1]); xb0[2] = f2bf(c0[2]); xb0[3] = f2bf(c0[3]);
            xb0[4] = f2bf(c1[0]); xb0[5] = f2bf(c1[1]); xb0[6] = f2bf(c1[2]); xb0[7] = f2bf(c1[3]);
            xb1[0] = f2bf(c2[0]); xb1[1] = f2bf(c2[1]); xb1[2] = f2bf(c2[2]); xb1[3] = f2bf(c2[3]);
            xb1[4] = f2bf(c3[0]); xb1[5] = f2bf(c3[1]); xb1[6] = f2bf(c3[2]); xb1[7] = f2bf(c3[3]);

            accA[0][0] = MFMA(xb0, ca0, accA[0][0]); accA[1][0] = MFMA(xb1, ca0, accA[1][0]);
            accB[0][0] = MFMA(xb0, sa0, accB[0][0]); accB[1][0] = MFMA(xb1, sa0, accB[1][0]);
            accA[0][1] = MFMA(xb0, ca1, accA[0][1]); accA[1][1] = MFMA(xb1, ca1, accA[1][1]);
            accB[0][1] = MFMA(xb0, sa1, accB[0][1]); accB[1][1] = MFMA(xb1, sa1, accB[1][1]);
            accA[0][2] = MFMA(xb0, ca2, accA[0][2]); accA[1][2] = MFMA(xb1, ca2, accA[1][2]);
            accB[0][2] = MFMA(xb0, sa2, accB[0][2]); accB[1][2] = MFMA(xb1, sa2, accB[1][2]);
            accA[0][3] = MFMA(xb0, ca3, accA[0][3]); accA[1][3] = MFMA(xb1, ca3, accA[1][3]);
            accB[0][3] = MFMA(xb0, sa3, accB[0][3]); accB[1][3] = MFMA(xb1, sa3, accB[1][3]);

            if (t < 7) {
                ca0 = nc0; ca1 = nc1; ca2 = nc2; ca3 = nc3;
                sa0 = ns0; sa1 = ns1; sa2 = ns2; sa3 = ns3;
            }
        }

        // phase C: D-frags -> LDS rows uh*64.. (b64 writes, swizzled)
        #pragma unroll
        for (int fi = 0; fi < 2; ++fi)
            #pragma unroll
            for (int fu = 0; fu < 4; ++fu) {
                int ul    = uh * 64 + fu * 16 + l15;   // LDS row 0..127
                int ibase = i0 + fi * 16 + lr4;        // 4 consecutive i
                int byte  = ul * 512 + ((ibase * 2) ^ ((ul & 7) << 4));
                bf16x4 a4, b4;
                #pragma unroll
                for (int r = 0; r < 4; ++r) {
                    a4[r] = f2bf(accA[fi][fu][r]);
                    b4[r] = f2bf(accB[fi][fu][r]);
                }
                *(bf16x4*)(lds + byte)         = a4;
                *(bf16x4*)(lds + 65536 + byte) = b4;
            }
    }
    __syncthreads();   // the ONE barrier

    // ================= stage 2: two 32x32 output tiles per wave =================
    const short8 smask = {(short)0x8000, (short)0x8000, (short)0x8000, (short)0x8000,
                          (short)0x8000, (short)0x8000, (short)0x8000, (short)0x8000};
    const int vt = wave & 3;             // v-slice of 32
    const short* __restrict__ tC0 = g_Ct + (vt * 32 +  0 + l15) * NN + lk8;
    const short* __restrict__ tC1 = g_Ct + (vt * 32 + 16 + l15) * NN + lk8;
    const short* __restrict__ tS0 = g_St + (vt * 32 +  0 + l15) * NN + lk8;
    const short* __restrict__ tS1 = g_St + (vt * 32 + 16 + l15) * NN + lk8;

    #pragma unroll 1
    for (int p = 0; p < 2; ++p) {
        const int ut = p * 2 + (wave >> 2);   // u-tile 0..3 (32 u each)
        f32x4 accR[2][2], accI[2][2];         // [fu][fv]
        #pragma unroll
        for (int fu = 0; fu < 2; ++fu)
            #pragma unroll
            for (int fv = 0; fv < 2; ++fv) {
                accR[fu][fv] = (f32x4){0.f, 0.f, 0.f, 0.f};
                accI[fu][fv] = (f32x4){0.f, 0.f, 0.f, 0.f};
            }
        const int iA = (wst & 7) * 32;
        const int iB = ((wst + 1) & 7) * 32;
        short8 ac0 = *(const short8*)(tC0 + iA), ac1 = *(const short8*)(tC1 + iA);
        short8 as0 = *(const short8*)(tS0 + iA), as1 = *(const short8*)(tS1 + iA);
        short8 bc0 = *(const short8*)(tC0 + iB), bc1 = *(const short8*)(tC1 + iB);
        short8 bs0 = *(const short8*)(tS0 + iB), bs1 = *(const short8*)(tS1 + iB);

        #pragma unroll
        for (int t = 0; t < 8; ++t) {
            const int is = ((t + wst) & 7) * 32;
            short8 cb0 = ac0, cb1 = ac1, sb0 = as0, sb1 = as1;
            ac0 = bc0; ac1 = bc1; as0 = bs0; as1 = bs1;
            if (t < 6) {   // issue table tile t+2
                const int in = ((t + 2 + wst) & 7) * 32;
                bc0 = *(const short8*)(tC0 + in); bc1 = *(const short8*)(tC1 + in);
                bs0 = *(const short8*)(tS0 + in); bs1 = *(const short8*)(tS1 + in);
            }
            short8 nb0 = sb0 ^ smask;
            short8 nb1 = sb1 ^ smask;
            short8 a[2], bn[2];
            #pragma unroll
            for (int fu = 0; fu < 2; ++fu) {
                int ul   = ut * 32 + fu * 16 + l15;
                int byte = ul * 512 + (((is + lk8) * 2) ^ ((ul & 7) << 4));
                a[fu]  = *(const short8*)(lds + byte);
                bn[fu] = *(const short8*)(lds + 65536 + byte);
            }
            // group 1: R += a*cb
            accR[0][0] = MFMA(a[0],  cb0, accR[0][0]);
            accR[1][0] = MFMA(a[1],  cb0, accR[1][0]);
            accR[0][1] = MFMA(a[0],  cb1, accR[0][1]);
            accR[1][1] = MFMA(a[1],  cb1, accR[1][1]);
            // group 2: I += bn*cb (independent)
            accI[0][0] = MFMA(bn[0], cb0, accI[0][0]);
            accI[1][0] = MFMA(bn[1], cb0, accI[1][0]);
            accI[0][1] = MFMA(bn[0], cb1, accI[0][1]);
            accI[1][1] = MFMA(bn[1], cb1, accI[1][1]);
            // group 3: R += bn*sb (dep on group 1, 8 insts back)
            accR[0][0] = MFMA(bn[0], sb0, accR[0][0]);
            accR[1][0] = MFMA(bn[1], sb0, accR[1][0]);
            accR[0][1] = MFMA(bn[0], sb1, accR[0][1]);
            accR[1][1] = MFMA(bn[1], sb1, accR[1][1]);
            // group 4: I += a*nb (dep on group 2, 8 insts back)
            accI[0][0] = MFMA(a[0],  nb0, accI[0][0]);
            accI[1][0] = MFMA(a[1],  nb0, accI[1][0]);
            accI[0][1] = MFMA(a[0],  nb1, accI[0][1]);
            accI[1][1] = MFMA(a[1],  nb1, accI[1][1]);
        }
        #pragma unroll
        for (int fu = 0; fu < 2; ++fu)
            #pragma unroll
            for (int fv = 0; fv < 2; ++fv)
                #pragma unroll
                for (int r = 0; r < 4; ++r) {
                    int u = ut * 32 + fu * 16 + lr4 + r;
                    int v = vt * 32 + fv * 16 + l15;
                    outR[u * KF + v] = accR[fu][fv][r];
                    outI[u * KF + v] = accI[fu][fv][r];
                }
    }
}

extern "C" void kernel_launch(void* const* d_in, const int* in_sizes, int n_in,
                              void* d_out, int out_size, void* d_ws, size_t ws_size,
                              hipStream_t stream) {
    const float* x = (const float*)d_in[0];
    float* out = (float*)d_out;
    hipFuncSetAttribute((const void*)freq_dft,
                        hipFuncAttributeMaxDynamicSharedMemorySize, 131072);
    gen_tables<<<dim3((KF * NN + 255) / 256), dim3(256), 0, stream>>>();
    freq_dft<<<dim3(NIMG), dim3(512), 131072, stream>>>(x, out);
}

// Round 9
// 134.465 us; speedup vs baseline: 1.6844x; 1.6844x over previous
//
#include <hip/hip_runtime.h>
#include <hip/hip_bf16.h>

// FrequencyLayer: separable real DFT via bf16 MFMA.
// real[b,c,u,v] = sum_{i,j} x[i,j] cos(2pi(j*u+i*v)/N)
// imag[b,c,u,v] = -sum_{i,j} x[i,j] sin(2pi(j*u+i*v)/N), N=256, u,v in [0,128)
//
// v9 = v7 (proven 160us bench) + parity-fold stage 2 + cvtpk:
//  - i-fold: cos(2pi i v/256) with i>=128 folds as (-1)^v cos(2pi(i-128)v/256).
//    Stage-1 waves own i-rows {16w..16w+15} and {+128}; fold e=lo+hi, o=lo-hi
//    on the f32 accumulators (free), LDS stores e at k<128, o at k>=128.
//  - Stage 2: K=256 -> 128; even-v outputs use e-operands, odd-v use o;
//    parity-reordered tables T2{cE,cO,sE,sO}[64][128]. MFMA + table loads halved.
//  - f32->bf16 via v_cvt_pk_bf16_f32 with v4's union pattern (v4 passed; its
//    slowdown was dynamic-indexed arrays, absent here; v5's bit_cast avoided).
//  - epilogue: even/odd v interleave -> coalesced float2 stores.

typedef __attribute__((ext_vector_type(8))) short short8;   // 8 bf16 = 4 VGPR
typedef __attribute__((ext_vector_type(4))) short bf16x4;   // 4 bf16 = 8B
typedef __attribute__((ext_vector_type(4))) float f32x4;    // MFMA C/D frag
typedef __attribute__((ext_vector_type(2))) float f32x2;

typedef union { short8 s8; unsigned u[4]; } pk8;            // v4-proven pattern
typedef union { bf16x4 s4; unsigned u[2]; } pk4;

#define NN 256
#define KF 128
#define NIMG 1024

__device__ __align__(16) short g_Ct[KF * NN];    // cos(2pi*u*j/256)  (stage 1)
__device__ __align__(16) short g_Stn[KF * NN];   // -sin(2pi*u*j/256) (stage 1)
// stage-2 parity tables: rows s=0..63 -> v=2s (E) or v=2s+1 (O); cols i=0..127
__device__ __align__(16) short g_T2cE[64 * 128];
__device__ __align__(16) short g_T2cO[64 * 128];
__device__ __align__(16) short g_T2sE[64 * 128];
__device__ __align__(16) short g_T2sO[64 * 128];

__device__ __forceinline__ short f2bf(float f) {
    union { float f; unsigned u; } v; v.f = f;
    unsigned r = v.u + 0x7FFFu + ((v.u >> 16) & 1u);  // RNE
    return (short)(r >> 16);
}

__device__ __forceinline__ unsigned cvtpk(float lo, float hi) {
    unsigned r;
    asm("v_cvt_pk_bf16_f32 %0, %1, %2" : "=v"(r) : "v"(lo), "v"(hi));
    return r;
}

__global__ void gen_tables() {
    int tid = blockIdx.x * blockDim.x + threadIdx.x;
    const float w = 0.02454369260617026f;            // 2pi/256
    if (tid < KF * NN) {
        int u = tid >> 8;
        int j = tid & 255;
        int phase = (u * j) & 255;
        float s, c;
        sincosf((float)phase * w, &s, &c);
        g_Ct[tid]  = f2bf(c);
        g_Stn[tid] = f2bf(-s);
    }
    if (tid < 64 * 128) {
        int s = tid >> 7;
        int i = tid & 127;
        int pe = (i * (2 * s)) & 255;
        int po = (i * (2 * s + 1)) & 255;
        float se, ce, so, co;
        sincosf((float)pe * w, &se, &ce);
        sincosf((float)po * w, &so, &co);
        g_T2cE[tid] = f2bf(ce);
        g_T2cO[tid] = f2bf(co);
        g_T2sE[tid] = f2bf(se);
        g_T2sO[tid] = f2bf(so);
    }
}

#define MFMA(a, b, c) __builtin_amdgcn_mfma_f32_16x16x32_bf16(a, b, c, 0, 0, 0)

__global__ __launch_bounds__(512, 4) void freq_dft(const float* __restrict__ x,
                                                   float* __restrict__ out) {
    // LDS (64KB), two lifetimes:
    //   phase A/B: Ct half [64u][256j] bf16 swizzled (32KB) | Stn half (32KB)
    //   phase C/D: eA|oA [64u][256k] (32KB) | eBn|oBn (32KB); o at k>=128
    __shared__ __align__(16) char lds[65536];

    // XCD-pairing decode: both h-half blocks of one image land on the same XCD.
    const int bid = blockIdx.x;
    const int cc  = bid & 7;
    const int q   = bid >> 3;
    const int h   = q & 1;
    const int img = cc + ((q >> 1) << 3);

    const float* __restrict__ X = x + (size_t)img * (NN * NN);
    float* __restrict__ outR = out + (size_t)img * (KF * KF);
    float* __restrict__ outI = outR + (size_t)NIMG * (KF * KF);

    const int lane = threadIdx.x & 63;
    const int wave = threadIdx.x >> 6;   // 0..7
    const int l15  = lane & 15;
    const int lk8  = (lane >> 4) << 3;   // A/B frag k-base (elems)
    const int lr4  = (lane >> 4) << 2;   // D frag row-base
    const int wst  = wave;               // stagger offset

    // ---------------- phase A: stage-1 tables -> LDS (swizzled) ----------------
    {
        const short* __restrict__ srcC = g_Ct  + h * 64 * NN;
        const short* __restrict__ srcS = g_Stn + h * 64 * NN;
        #pragma unroll
        for (int k = 0; k < 4; ++k) {
            int slot = threadIdx.x + k * 512;        // 16B-chunk index, 0..2047
            int row  = slot >> 5;                    // 0..63
            int chk  = slot & 31;                    // 16B chunk within row
            int byte = row * 512 + ((chk << 4) ^ ((row & 7) << 4));
            short8 vC = *(const short8*)(srcC + row * NN + chk * 8);
            short8 vS = *(const short8*)(srcS + row * NN + chk * 8);
            *(short8*)(lds + byte)         = vC;
            *(short8*)(lds + 32768 + byte) = vS;
        }
    }
    __syncthreads();

    // ------- phase B: stage 1. Wave rows {16w..16w+15} and {+128} (fold pairs) -----
    f32x4 accA[2][4], accB[2][4];    // [fi: lo/hi][fu] : D[i][u] fragments
    {
        const int i0 = wave * 16;
        #pragma unroll
        for (int fi = 0; fi < 2; ++fi)
            #pragma unroll
            for (int fu = 0; fu < 4; ++fu) {
                accA[fi][fu] = (f32x4){0.f, 0.f, 0.f, 0.f};
                accB[fi][fu] = (f32x4){0.f, 0.f, 0.f, 0.f};
            }
        const float* __restrict__ xp0 = X + (i0 + l15) * NN + lk8;         // lo rows
        const float* __restrict__ xp1 = X + (i0 + 128 + l15) * NN + lk8;   // hi rows
        const int jA = (wst & 7) * 32;
        const int jB = ((wst + 1) & 7) * 32;
        f32x4 a0 = *(const f32x4*)(xp0 + jA), a1 = *(const f32x4*)(xp0 + jA + 4);
        f32x4 a2 = *(const f32x4*)(xp1 + jA), a3 = *(const f32x4*)(xp1 + jA + 4);
        f32x4 b0 = *(const f32x4*)(xp0 + jB), b1 = *(const f32x4*)(xp0 + jB + 4);
        f32x4 b2 = *(const f32x4*)(xp1 + jB), b3 = *(const f32x4*)(xp1 + jB + 4);
        #pragma unroll
        for (int t = 0; t < 8; ++t) {
            const int j0 = ((t + wst) & 7) * 32;
            f32x4 c0 = a0, c1 = a1, c2 = a2, c3 = a3;
            a0 = b0; a1 = b1; a2 = b2; a3 = b3;
            if (t < 6) {   // issue X tile t+2
                const int jn = ((t + 2 + wst) & 7) * 32;
                b0 = *(const f32x4*)(xp0 + jn); b1 = *(const f32x4*)(xp0 + jn + 4);
                b2 = *(const f32x4*)(xp1 + jn); b3 = *(const f32x4*)(xp1 + jn + 4);
            }
            pk8 x0u, x1u;
            x0u.u[0] = cvtpk(c0[0], c0[1]); x0u.u[1] = cvtpk(c0[2], c0[3]);
            x0u.u[2] = cvtpk(c1[0], c1[1]); x0u.u[3] = cvtpk(c1[2], c1[3]);
            x1u.u[0] = cvtpk(c2[0], c2[1]); x1u.u[1] = cvtpk(c2[2], c2[3]);
            x1u.u[2] = cvtpk(c3[0], c3[1]); x1u.u[3] = cvtpk(c3[2], c3[3]);
            short8 xb0 = x0u.s8;
            short8 xb1 = x1u.s8;
            short8 ca[4], sa[4];
            #pragma unroll
            for (int fu = 0; fu < 4; ++fu) {
                int row  = fu * 16 + l15;
                int byte = row * 512 + (((j0 + lk8) * 2) ^ ((row & 7) << 4));
                ca[fu] = *(const short8*)(lds + byte);
                sa[fu] = *(const short8*)(lds + 32768 + byte);
            }
            #pragma unroll
            for (int fu = 0; fu < 4; ++fu) {
                accA[0][fu] = MFMA(xb0, ca[fu], accA[0][fu]);
                accA[1][fu] = MFMA(xb1, ca[fu], accA[1][fu]);
                accB[0][fu] = MFMA(xb0, sa[fu], accB[0][fu]);
                accB[1][fu] = MFMA(xb1, sa[fu], accB[1][fu]);
            }
        }
    }
    __syncthreads();   // all table reads done; LDS region can be overwritten

    // ------ phase C: fold on f32 acc (e=lo+hi, o=lo-hi), b64 writes swizzled ------
    {
        const int kb = wave * 16 + lr4;              // folded k-slot base (4 consec)
        #pragma unroll
        for (int fu = 0; fu < 4; ++fu) {
            f32x4 eA = accA[0][fu] + accA[1][fu];
            f32x4 oA = accA[0][fu] - accA[1][fu];
            f32x4 eB = accB[0][fu] + accB[1][fu];
            f32x4 oB = accB[0][fu] - accB[1][fu];
            int ul  = fu * 16 + l15;                 // u row 0..63
            int sw  = (ul & 7) << 4;
            int byE = ul * 512 + ((kb * 2) ^ sw);
            int byO = ul * 512 + (((kb + 128) * 2) ^ sw);
            pk4 ea, oa, eb, ob;
            ea.u[0] = cvtpk(eA[0], eA[1]); ea.u[1] = cvtpk(eA[2], eA[3]);
            oa.u[0] = cvtpk(oA[0], oA[1]); oa.u[1] = cvtpk(oA[2], oA[3]);
            eb.u[0] = cvtpk(eB[0], eB[1]); eb.u[1] = cvtpk(eB[2], eB[3]);
            ob.u[0] = cvtpk(oB[0], oB[1]); ob.u[1] = cvtpk(oB[2], oB[3]);
            *(bf16x4*)(lds + byE)         = ea.s4;
            *(bf16x4*)(lds + byO)         = oa.s4;
            *(bf16x4*)(lds + 32768 + byE) = eb.s4;
            *(bf16x4*)(lds + 32768 + byO) = ob.s4;
        }
    }
    __syncthreads();

    // -------- phase D: stage 2, K=128 folded, parity tables, 2-deep prefetch -------
    {
        const int wu = wave >> 2;        // 0..1 : u-slice of 32
        const int vt = wave & 3;         // 0..3 : v-slice of 32 (16 even + 16 odd)
        const short8 smask = {(short)0x8000, (short)0x8000, (short)0x8000, (short)0x8000,
                              (short)0x8000, (short)0x8000, (short)0x8000, (short)0x8000};
        f32x4 accRE[2], accRO[2], accIE[2], accIO[2];
        #pragma unroll
        for (int fu = 0; fu < 2; ++fu) {
            accRE[fu] = (f32x4){0.f, 0.f, 0.f, 0.f};
            accRO[fu] = (f32x4){0.f, 0.f, 0.f, 0.f};
            accIE[fu] = (f32x4){0.f, 0.f, 0.f, 0.f};
            accIO[fu] = (f32x4){0.f, 0.f, 0.f, 0.f};
        }
        const short* __restrict__ pcE = g_T2cE + (vt * 16 + l15) * 128 + lk8;
        const short* __restrict__ pcO = g_T2cO + (vt * 16 + l15) * 128 + lk8;
        const short* __restrict__ psE = g_T2sE + (vt * 16 + l15) * 128 + lk8;
        const short* __restrict__ psO = g_T2sO + (vt * 16 + l15) * 128 + lk8;
        const int iA = (wst & 3) * 32;
        const int iB = ((wst + 1) & 3) * 32;
        short8 AcE = *(const short8*)(pcE + iA), AcO = *(const short8*)(pcO + iA);
        short8 AsE = *(const short8*)(psE + iA), AsO = *(const short8*)(psO + iA);
        short8 BcE = *(const short8*)(pcE + iB), BcO = *(const short8*)(pcO + iB);
        short8 BsE = *(const short8*)(psE + iB), BsO = *(const short8*)(psO + iB);
        #pragma unroll
        for (int t = 0; t < 4; ++t) {
            const int is = ((t + wst) & 3) * 32;
            short8 cE = AcE, cO = AcO, sE = AsE, sO = AsO;
            AcE = BcE; AcO = BcO; AsE = BsE; AsO = BsO;
            if (t < 2) {   // issue tile t+2
                const int in = ((t + 2 + wst) & 3) * 32;
                BcE = *(const short8*)(pcE + in); BcO = *(const short8*)(pcO + in);
                BsE = *(const short8*)(psE + in); BsO = *(const short8*)(psO + in);
            }
            short8 sEn = sE ^ smask;
            short8 sOn = sO ^ smask;
            short8 eA[2], oA[2], eB[2], oB[2];
            #pragma unroll
            for (int fu = 0; fu < 2; ++fu) {
                int ul  = wu * 32 + fu * 16 + l15;
                int sw  = (ul & 7) << 4;
                int byE = ul * 512 + (((is + lk8) * 2) ^ sw);
                int byO = ul * 512 + (((is + 128 + lk8) * 2) ^ sw);
                eA[fu] = *(const short8*)(lds + byE);
                oA[fu] = *(const short8*)(lds + byO);
                eB[fu] = *(const short8*)(lds + 32768 + byE);
                oB[fu] = *(const short8*)(lds + 32768 + byO);
            }
            // 8 independent accs first:
            accRE[0] = MFMA(eA[0], cE, accRE[0]); accRE[1] = MFMA(eA[1], cE, accRE[1]);
            accRO[0] = MFMA(oA[0], cO, accRO[0]); accRO[1] = MFMA(oA[1], cO, accRO[1]);
            accIE[0] = MFMA(eB[0], cE, accIE[0]); accIE[1] = MFMA(eB[1], cE, accIE[1]);
            accIO[0] = MFMA(oB[0], cO, accIO[0]); accIO[1] = MFMA(oB[1], cO, accIO[1]);
            // dependent set, distance 8:
            accRE[0] = MFMA(eB[0], sE, accRE[0]); accRE[1] = MFMA(eB[1], sE, accRE[1]);
            accRO[0] = MFMA(oB[0], sO, accRO[0]); accRO[1] = MFMA(oB[1], sO, accRO[1]);
            accIE[0] = MFMA(eA[0], sEn, accIE[0]); accIE[1] = MFMA(eA[1], sEn, accIE[1]);
            accIO[0] = MFMA(oA[0], sOn, accIO[0]); accIO[1] = MFMA(oA[1], sOn, accIO[1]);
        }
        #pragma unroll
        for (int fu = 0; fu < 2; ++fu)
            #pragma unroll
            for (int r = 0; r < 4; ++r) {
                int u = h * 64 + wu * 32 + fu * 16 + lr4 + r;
                int v = vt * 32 + 2 * l15;            // even/odd interleave
                f32x2 vr = {accRE[fu][r], accRO[fu][r]};
                f32x2 vi = {accIE[fu][r], accIO[fu][r]};
                *(f32x2*)(outR + u * KF + v) = vr;
                *(f32x2*)(outI + u * KF + v) = vi;
            }
    }
}

extern "C" void kernel_launch(void* const* d_in, const int* in_sizes, int n_in,
                              void* d_out, int out_size, void* d_ws, size_t ws_size,
                              hipStream_t stream) {
    const float* x = (const float*)d_in[0];
    float* out = (float*)d_out;
    gen_tables<<<dim3((KF * NN + 255) / 256), dim3(256), 0, stream>>>();
    freq_dft<<<dim3(NIMG * 2), dim3(512), 0, stream>>>(x, out);
}

// Round 10
// 133.974 us; speedup vs baseline: 1.6906x; 1.0037x over previous
//
#include <hip/hip_runtime.h>
#include <hip/hip_bf16.h>

// FrequencyLayer: separable real DFT via bf16 MFMA.
// real[b,c,u,v] = sum_{i,j} x[i,j] cos(2pi(j*u+i*v)/N)
// imag[b,c,u,v] = -sum_{i,j} x[i,j] sin(2pi(j*u+i*v)/N), N=256, u,v in [0,128)
//
// v10 = v9 (proven 134us) + stage-1 j-parity fold:
//  - j-fold: cos(2pi(j+128)u/256) = (-1)^u cos(2pi j u/256). Stage 1 K=256->128:
//    even-u rows consume e=x[j]+x[j+128], odd-u rows o=x[j]-x[j+128] (f32 fold).
//    Stage-1 MFMA and table-LDS reads halve.
//  - unified tables: stage-1 parity tables == stage-2 parity tables (4 x [64][128]:
//    cE,cO,sE,sO). Stage-1's -sin obtained by sign-XOR at LDS staging (bit-exact).
//  - phase C write mapping: fragment fu -> ul = 2*((fu&1)*16+l15) + (fu>>1);
//    LDS content identical to v9, phase D unchanged.
//  - X prefetch 1-deep, two-batch issue (iLo before even-MFMAs, iHi before odd)
//    to keep VGPR+AGPR <= 128.

typedef __attribute__((ext_vector_type(8))) short short8;   // 8 bf16 = 4 VGPR
typedef __attribute__((ext_vector_type(4))) short bf16x4;   // 4 bf16 = 8B
typedef __attribute__((ext_vector_type(4))) float f32x4;    // MFMA C/D frag
typedef __attribute__((ext_vector_type(2))) float f32x2;

typedef union { short8 s8; unsigned u[4]; } pk8;            // v9-proven pattern
typedef union { bf16x4 s4; unsigned u[2]; } pk4;

#define NN 256
#define KF 128
#define NIMG 1024

// unified parity tables, rows m=0..63 -> freq 2m (E) / 2m+1 (O); cols j=0..127
__device__ __align__(16) short gcE[64 * 128];
__device__ __align__(16) short gcO[64 * 128];
__device__ __align__(16) short gsE[64 * 128];
__device__ __align__(16) short gsO[64 * 128];

__device__ __forceinline__ short f2bf(float f) {
    union { float f; unsigned u; } v; v.f = f;
    unsigned r = v.u + 0x7FFFu + ((v.u >> 16) & 1u);  // RNE
    return (short)(r >> 16);
}

__device__ __forceinline__ unsigned cvtpk(float lo, float hi) {
    unsigned r;
    asm("v_cvt_pk_bf16_f32 %0, %1, %2" : "=v"(r) : "v"(lo), "v"(hi));
    return r;
}

__global__ void gen_tables() {
    int tid = blockIdx.x * blockDim.x + threadIdx.x;
    if (tid >= 64 * 128) return;
    const float w = 0.02454369260617026f;            // 2pi/256
    int m = tid >> 7;
    int j = tid & 127;
    int pe = (j * (2 * m)) & 255;
    int po = (j * (2 * m + 1)) & 255;
    float se, ce, so, co;
    sincosf((float)pe * w, &se, &ce);
    sincosf((float)po * w, &so, &co);
    gcE[tid] = f2bf(ce);
    gcO[tid] = f2bf(co);
    gsE[tid] = f2bf(se);
    gsO[tid] = f2bf(so);
}

#define MFMA(a, b, c) __builtin_amdgcn_mfma_f32_16x16x32_bf16(a, b, c, 0, 0, 0)

__global__ __launch_bounds__(512, 4) void freq_dft(const float* __restrict__ x,
                                                   float* __restrict__ out) {
    // LDS (64KB), two lifetimes:
    //   phase A/B: Ctab [64][128] bf16 swz (16KB) @0 | Stab (-sin, 16KB) @16384
    //   phase C/D: eA|oA [64u][256k] (32KB) @0 | eBn|oBn (32KB) @32768
    __shared__ __align__(16) char lds[65536];

    // XCD-pairing decode: both h-half blocks of one image land on the same XCD.
    const int bid = blockIdx.x;
    const int cc  = bid & 7;
    const int q   = bid >> 3;
    const int h   = q & 1;
    const int img = cc + ((q >> 1) << 3);

    const float* __restrict__ X = x + (size_t)img * (NN * NN);
    float* __restrict__ outR = out + (size_t)img * (KF * KF);
    float* __restrict__ outI = outR + (size_t)NIMG * (KF * KF);

    const int lane = threadIdx.x & 63;
    const int wave = threadIdx.x >> 6;   // 0..7
    const int l15  = lane & 15;
    const int lk8  = (lane >> 4) << 3;   // A/B frag k-base (elems)
    const int lr4  = (lane >> 4) << 2;   // D frag row-base
    const int wst  = wave;               // stagger offset

    const short8 smask = {(short)0x8000, (short)0x8000, (short)0x8000, (short)0x8000,
                          (short)0x8000, (short)0x8000, (short)0x8000, (short)0x8000};

    // ---------------- phase A: parity tables -> LDS (swizzled; sin negated) --------
    {
        #pragma unroll
        for (int k = 0; k < 2; ++k) {      // Ctab: 1024 x 16B chunks
            int c   = threadIdx.x + k * 512;
            int row = c >> 4, chk = c & 15;
            int byte = row * 256 + ((chk << 4) ^ ((row & 7) << 4));
            const short* src = (row < 32 ? gcE + (h * 32 + row) * 128
                                         : gcO + (h * 32 + row - 32) * 128) + chk * 8;
            *(short8*)(lds + byte) = *(const short8*)src;
        }
        #pragma unroll
        for (int k = 0; k < 2; ++k) {      // Stab = -sin
            int c   = threadIdx.x + k * 512;
            int row = c >> 4, chk = c & 15;
            int byte = row * 256 + ((chk << 4) ^ ((row & 7) << 4));
            const short* src = (row < 32 ? gsE + (h * 32 + row) * 128
                                         : gsO + (h * 32 + row - 32) * 128) + chk * 8;
            short8 v = *(const short8*)src;
            *(short8*)(lds + 16384 + byte) = v ^ smask;
        }
    }
    __syncthreads();

    // ------- phase B: stage 1, K=128 j-folded, parity tables from LDS --------------
    f32x4 accA[2][4], accB[2][4];    // [fi: iLo/iHi][fu: 0,1 even-u | 2,3 odd-u]
    {
        const int i0 = wave * 16;
        #pragma unroll
        for (int fi = 0; fi < 2; ++fi)
            #pragma unroll
            for (int fu = 0; fu < 4; ++fu) {
                accA[fi][fu] = (f32x4){0.f, 0.f, 0.f, 0.f};
                accB[fi][fu] = (f32x4){0.f, 0.f, 0.f, 0.f};
            }
        const float* __restrict__ xL = X + (i0 + l15) * NN + lk8;        // iLo rows
        const float* __restrict__ xH = X + (i0 + 128 + l15) * NN + lk8;  // iHi rows
        const int jP = (wst & 3) * 32;
        f32x4 r0 = *(const f32x4*)(xL + jP),       r1 = *(const f32x4*)(xL + jP + 4);
        f32x4 r2 = *(const f32x4*)(xL + jP + 128), r3 = *(const f32x4*)(xL + jP + 132);
        f32x4 r4 = *(const f32x4*)(xH + jP),       r5 = *(const f32x4*)(xH + jP + 4);
        f32x4 r6 = *(const f32x4*)(xH + jP + 128), r7 = *(const f32x4*)(xH + jP + 132);
        #pragma unroll
        for (int t = 0; t < 4; ++t) {
            const int j0 = ((t + wst) & 3) * 32;
            // fold (f32, exact) + convert; pairwise so raw regs die early
            pk8 xeL, xoL, xeH, xoH;
            {
                f32x4 e = r0 + r2, o = r0 - r2;
                xeL.u[0] = cvtpk(e[0], e[1]); xeL.u[1] = cvtpk(e[2], e[3]);
                xoL.u[0] = cvtpk(o[0], o[1]); xoL.u[1] = cvtpk(o[2], o[3]);
            }
            {
                f32x4 e = r1 + r3, o = r1 - r3;
                xeL.u[2] = cvtpk(e[0], e[1]); xeL.u[3] = cvtpk(e[2], e[3]);
                xoL.u[2] = cvtpk(o[0], o[1]); xoL.u[3] = cvtpk(o[2], o[3]);
            }
            {
                f32x4 e = r4 + r6, o = r4 - r6;
                xeH.u[0] = cvtpk(e[0], e[1]); xeH.u[1] = cvtpk(e[2], e[3]);
                xoH.u[0] = cvtpk(o[0], o[1]); xoH.u[1] = cvtpk(o[2], o[3]);
            }
            {
                f32x4 e = r5 + r7, o = r5 - r7;
                xeH.u[2] = cvtpk(e[0], e[1]); xeH.u[3] = cvtpk(e[2], e[3]);
                xoH.u[2] = cvtpk(o[0], o[1]); xoH.u[3] = cvtpk(o[2], o[3]);
            }
            short8 XE0 = xeL.s8, XO0 = xoL.s8, XE1 = xeH.s8, XO1 = xoH.s8;
            // batch 1: issue next tile's iLo loads
            if (t < 3) {
                const int jn = ((t + 1 + wst) & 3) * 32;
                r0 = *(const f32x4*)(xL + jn);       r1 = *(const f32x4*)(xL + jn + 4);
                r2 = *(const f32x4*)(xL + jn + 128); r3 = *(const f32x4*)(xL + jn + 132);
            }
            // even-u tables + MFMA
            short8 ca0, ca1, sa0, sa1;
            {
                int row = l15;
                int byte = row * 256 + (((j0 + lk8) * 2) ^ ((row & 7) << 4));
                ca0 = *(const short8*)(lds + byte);
                sa0 = *(const short8*)(lds + 16384 + byte);
            }
            {
                int row = 16 + l15;
                int byte = row * 256 + (((j0 + lk8) * 2) ^ ((row & 7) << 4));
                ca1 = *(const short8*)(lds + byte);
                sa1 = *(const short8*)(lds + 16384 + byte);
            }
            accA[0][0] = MFMA(XE0, ca0, accA[0][0]); accA[1][0] = MFMA(XE1, ca0, accA[1][0]);
            accB[0][0] = MFMA(XE0, sa0, accB[0][0]); accB[1][0] = MFMA(XE1, sa0, accB[1][0]);
            accA[0][1] = MFMA(XE0, ca1, accA[0][1]); accA[1][1] = MFMA(XE1, ca1, accA[1][1]);
            accB[0][1] = MFMA(XE0, sa1, accB[0][1]); accB[1][1] = MFMA(XE1, sa1, accB[1][1]);
            // batch 2: issue next tile's iHi loads
            if (t < 3) {
                const int jn = ((t + 1 + wst) & 3) * 32;
                r4 = *(const f32x4*)(xH + jn);       r5 = *(const f32x4*)(xH + jn + 4);
                r6 = *(const f32x4*)(xH + jn + 128); r7 = *(const f32x4*)(xH + jn + 132);
            }
            // odd-u tables + MFMA
            short8 ca2, ca3, sa2, sa3;
            {
                int row = 32 + l15;
                int byte = row * 256 + (((j0 + lk8) * 2) ^ ((row & 7) << 4));
                ca2 = *(const short8*)(lds + byte);
                sa2 = *(const short8*)(lds + 16384 + byte);
            }
            {
                int row = 48 + l15;
                int byte = row * 256 + (((j0 + lk8) * 2) ^ ((row & 7) << 4));
                ca3 = *(const short8*)(lds + byte);
                sa3 = *(const short8*)(lds + 16384 + byte);
            }
            accA[0][2] = MFMA(XO0, ca2, accA[0][2]); accA[1][2] = MFMA(XO1, ca2, accA[1][2]);
            accB[0][2] = MFMA(XO0, sa2, accB[0][2]); accB[1][2] = MFMA(XO1, sa2, accB[1][2]);
            accA[0][3] = MFMA(XO0, ca3, accA[0][3]); accA[1][3] = MFMA(XO1, ca3, accA[1][3]);
            accB[0][3] = MFMA(XO0, sa3, accB[0][3]); accB[1][3] = MFMA(XO1, sa3, accB[1][3]);
        }
    }
    __syncthreads();   // all table reads done; LDS region can be overwritten

    // ------ phase C: i-fold on f32 acc (e=lo+hi, o=lo-hi), b64 writes swizzled ------
    {
        const int kb = wave * 16 + lr4;              // folded i-slot base (4 consec)
        #pragma unroll
        for (int fu = 0; fu < 4; ++fu) {
            f32x4 eA = accA[0][fu] + accA[1][fu];
            f32x4 oA = accA[0][fu] - accA[1][fu];
            f32x4 eB = accB[0][fu] + accB[1][fu];
            f32x4 oB = accB[0][fu] - accB[1][fu];
            int ul  = 2 * ((fu & 1) * 16 + l15) + (fu >> 1);   // u row 0..63
            int sw  = (ul & 7) << 4;
            int byE = ul * 512 + ((kb * 2) ^ sw);
            int byO = ul * 512 + (((kb + 128) * 2) ^ sw);
            pk4 ea, oa, eb, ob;
            ea.u[0] = cvtpk(eA[0], eA[1]); ea.u[1] = cvtpk(eA[2], eA[3]);
            oa.u[0] = cvtpk(oA[0], oA[1]); oa.u[1] = cvtpk(oA[2], oA[3]);
            eb.u[0] = cvtpk(eB[0], eB[1]); eb.u[1] = cvtpk(eB[2], eB[3]);
            ob.u[0] = cvtpk(oB[0], oB[1]); ob.u[1] = cvtpk(oB[2], oB[3]);
            *(bf16x4*)(lds + byE)         = ea.s4;
            *(bf16x4*)(lds + byO)         = oa.s4;
            *(bf16x4*)(lds + 32768 + byE) = eb.s4;
            *(bf16x4*)(lds + 32768 + byO) = ob.s4;
        }
    }
    __syncthreads();

    // -------- phase D: stage 2, K=128 folded, parity tables, 2-deep prefetch -------
    {
        const int wu = wave >> 2;        // 0..1 : u-slice of 32
        const int vt = wave & 3;         // 0..3 : v-slice of 32 (16 even + 16 odd)
        f32x4 accRE[2], accRO[2], accIE[2], accIO[2];
        #pragma unroll
        for (int fu = 0; fu < 2; ++fu) {
            accRE[fu] = (f32x4){0.f, 0.f, 0.f, 0.f};
            accRO[fu] = (f32x4){0.f, 0.f, 0.f, 0.f};
            accIE[fu] = (f32x4){0.f, 0.f, 0.f, 0.f};
            accIO[fu] = (f32x4){0.f, 0.f, 0.f, 0.f};
        }
        const short* __restrict__ pcE = gcE + (vt * 16 + l15) * 128 + lk8;
        const short* __restrict__ pcO = gcO + (vt * 16 + l15) * 128 + lk8;
        const short* __restrict__ psE = gsE + (vt * 16 + l15) * 128 + lk8;
        const short* __restrict__ psO = gsO + (vt * 16 + l15) * 128 + lk8;
        const int iA = (wst & 3) * 32;
        const int iB = ((wst + 1) & 3) * 32;
        short8 AcE = *(const short8*)(pcE + iA), AcO = *(const short8*)(pcO + iA);
        short8 AsE = *(const short8*)(psE + iA), AsO = *(const short8*)(psO + iA);
        short8 BcE = *(const short8*)(pcE + iB), BcO = *(const short8*)(pcO + iB);
        short8 BsE = *(const short8*)(psE + iB), BsO = *(const short8*)(psO + iB);
        #pragma unroll
        for (int t = 0; t < 4; ++t) {
            const int is = ((t + wst) & 3) * 32;
            short8 cE = AcE, cO = AcO, sE = AsE, sO = AsO;
            AcE = BcE; AcO = BcO; AsE = BsE; AsO = BsO;
            if (t < 2) {   // issue tile t+2
                const int in = ((t + 2 + wst) & 3) * 32;
                BcE = *(const short8*)(pcE + in); BcO = *(const short8*)(pcO + in);
                BsE = *(const short8*)(psE + in); BsO = *(const short8*)(psO + in);
            }
            short8 sEn = sE ^ smask;
            short8 sOn = sO ^ smask;
            short8 eA[2], oA[2], eB[2], oB[2];
            #pragma unroll
            for (int fu = 0; fu < 2; ++fu) {
                int ul  = wu * 32 + fu * 16 + l15;
                int sw  = (ul & 7) << 4;
                int byE = ul * 512 + (((is + lk8) * 2) ^ sw);
                int byO = ul * 512 + (((is + 128 + lk8) * 2) ^ sw);
                eA[fu] = *(const short8*)(lds + byE);
                oA[fu] = *(const short8*)(lds + byO);
                eB[fu] = *(const short8*)(lds + 32768 + byE);
                oB[fu] = *(const short8*)(lds + 32768 + byO);
            }
            // 8 independent accs first:
            accRE[0] = MFMA(eA[0], cE, accRE[0]); accRE[1] = MFMA(eA[1], cE, accRE[1]);
            accRO[0] = MFMA(oA[0], cO, accRO[0]); accRO[1] = MFMA(oA[1], cO, accRO[1]);
            accIE[0] = MFMA(eB[0], cE, accIE[0]); accIE[1] = MFMA(eB[1], cE, accIE[1]);
            accIO[0] = MFMA(oB[0], cO, accIO[0]); accIO[1] = MFMA(oB[1], cO, accIO[1]);
            // dependent set, distance 8:
            accRE[0] = MFMA(eB[0], sE, accRE[0]); accRE[1] = MFMA(eB[1], sE, accRE[1]);
            accRO[0] = MFMA(oB[0], sO, accRO[0]); accRO[1] = MFMA(oB[1], sO, accRO[1]);
            accIE[0] = MFMA(eA[0], sEn, accIE[0]); accIE[1] = MFMA(eA[1], sEn, accIE[1]);
            accIO[0] = MFMA(oA[0], sOn, accIO[0]); accIO[1] = MFMA(oA[1], sOn, accIO[1]);
        }
        #pragma unroll
        for (int fu = 0; fu < 2; ++fu)
            #pragma unroll
            for (int r = 0; r < 4; ++r) {
                int u = h * 64 + wu * 32 + fu * 16 + lr4 + r;
                int v = vt * 32 + 2 * l15;            // even/odd interleave
                f32x2 vr = {accRE[fu][r], accRO[fu][r]};
                f32x2 vi = {accIE[fu][r], accIO[fu][r]};
                *(f32x2*)(outR + u * KF + v) = vr;
                *(f32x2*)(outI + u * KF + v) = vi;
            }
    }
}

extern "C" void kernel_launch(void* const* d_in, const int* in_sizes, int n_in,
                              void* d_out, int out_size, void* d_ws, size_t ws_size,
                              hipStream_t stream) {
    const float* x = (const float*)d_in[0];
    float* out = (float*)d_out;
    gen_tables<<<dim3(32), dim3(256), 0, stream>>>();
    freq_dft<<<dim3(NIMG * 2), dim3(512), 0, stream>>>(x, out);
}